// Round 1
// 565.404 us; speedup vs baseline: 1.1844x; 1.1844x over previous
//
#include <hip/hip_runtime.h>

// Problem constants (from reference)
#define NE_  100000   // entities
#define NB_  1024     // batch
#define DD_  200      // embedding dim = P = K (true)
#define PP_  224      // padded K (multiple of 32) for staging layout

typedef _Float16 h8  __attribute__((ext_vector_type(8)));
typedef float    fx4 __attribute__((ext_vector_type(4)));
typedef float    fx16 __attribute__((ext_vector_type(16)));

__device__ __forceinline__ float fast_sigmoid(float x) {
    float e = __builtin_amdgcn_exp2f(-1.44269504088896340736f * x);
    return __builtin_amdgcn_rcpf(1.0f + e);
}

// ---------------------------------------------------------------------------
// Kernel 1: g16[b][j] = fp16( ((r@F0)*(e1@F1)*(t@F3)) @ F2^T )[b][j]
// Algebraic restructure: x = h @ (E@F2)^T = (h @ F2^T) @ E^T, so we fold the
// tiny 1024x200 @ 200x200 projection into prep and NEVER materialize FE.
// 256 blocks x 4 batch rows. Phase 1: h rows via uniform-row FMA loop (fp32).
// Phase 2: transpose through LDS, g = h @ F2^T (fp32), round to fp16, zero-pad.
// ---------------------------------------------------------------------------
__global__ __launch_bounds__(256) void prep_kernel(
    const int*   __restrict__ e1_idx, const int* __restrict__ r_idx,
    const int*   __restrict__ t_idx,
    const float* __restrict__ E, const float* __restrict__ R,
    const float* __restrict__ T,
    const float* __restrict__ F0, const float* __restrict__ F1,
    const float* __restrict__ F2, const float* __restrict__ F3,
    _Float16* __restrict__ g16)
{
    __shared__ __align__(16) float hl[4][DD_];
    const int tid = threadIdx.x;
    const int rb  = blockIdx.x * 4;             // 4 batch rows per block

    const float* rrow[4];
    const float* erow[4];
    const float* trow[4];
    #pragma unroll
    for (int i = 0; i < 4; ++i) {               // uniform -> SGPR row bases
        rrow[i] = R + (size_t)r_idx[rb + i]  * DD_;
        erow[i] = E + (size_t)e1_idx[rb + i] * DD_;
        trow[i] = T + (size_t)t_idx[rb + i]  * DD_;
    }

    const int p = tid;                          // rank index (phase 1)
    if (p < DD_) {
        float fr[4], fe[4], ft[4];
        #pragma unroll
        for (int i = 0; i < 4; ++i) { fr[i] = 0.f; fe[i] = 0.f; ft[i] = 0.f; }
        #pragma unroll 4
        for (int k = 0; k < DD_; ++k) {
            float f0 = F0[k * DD_ + p];         // coalesced across threads
            float f1 = F1[k * DD_ + p];
            float f3 = F3[k * DD_ + p];
            #pragma unroll
            for (int i = 0; i < 4; ++i) {       // uniform scalar loads
                fr[i] = fmaf(rrow[i][k], f0, fr[i]);
                fe[i] = fmaf(erow[i][k], f1, fe[i]);
                ft[i] = fmaf(trow[i][k], f3, ft[i]);
            }
        }
        #pragma unroll
        for (int i = 0; i < 4; ++i)
            hl[i][p] = fr[i] * fe[i] * ft[i];   // h row -> LDS (transpose hop)
    }
    __syncthreads();

    const int j = tid;                          // output column of g (phase 2)
    if (j < PP_) {
        float g[4] = {0.f, 0.f, 0.f, 0.f};
        if (j < DD_) {
            const float* f2r = F2 + (size_t)j * DD_;   // thread-private row stream
            for (int p4 = 0; p4 < DD_; p4 += 4) {
                fx4 f2v = *(const fx4*)(f2r + p4);
                #pragma unroll
                for (int i = 0; i < 4; ++i) {
                    fx4 hv = *(const fx4*)&hl[i][p4];  // LDS broadcast (free)
                    g[i] = fmaf(hv[0], f2v[0], g[i]);
                    g[i] = fmaf(hv[1], f2v[1], g[i]);
                    g[i] = fmaf(hv[2], f2v[2], g[i]);
                    g[i] = fmaf(hv[3], f2v[3], g[i]);
                }
            }
        }
        #pragma unroll
        for (int i = 0; i < 4; ++i)             // cols 200..223 written as 0
            g16[(size_t)(rb + i) * PP_ + j] = (_Float16)g[i];
    }
}

// ---------------------------------------------------------------------------
// Kernel 2: out = sigmoid(g @ E^T) via mfma_f32_32x32x16_f16.
// B-operand is E itself, converted fp32->fp16 in-register (one rounding,
// no FE materialization). K = 200 -> 13 MFMA steps (k>=200 pads are zero in g,
// and the single half-frag at k=200..207 is zeroed on the E side too).
// Block: 64 entity cols x full M=1024 in 16 chunks of 64 rows.
// LDS 64x232 fp16 = 29.7 KB -> 4 blocks/CU. C layout: col=lane&31.
// ---------------------------------------------------------------------------
__global__ __launch_bounds__(256, 4) void score_kernel(
    const _Float16* __restrict__ g16, const float* __restrict__ E,
    float* __restrict__ out)
{
    __shared__ __align__(16) _Float16 Alds[64 * 232];  // pitch 232: conflict-free b128

    const int tid = threadIdx.x;
    const int w   = tid >> 6;
    const int l   = tid & 63;
    const int l31 = l & 31;
    const int lh  = l >> 5;
    const int wm  = w & 1;                  // row half within 64-row chunk
    const int wn  = w >> 1;                 // col half within 64-col block tile
    const int nb  = blockIdx.x * 64;

    // Preload B fragments: E rows for this wave's 32 entity cols, cvt to fp16.
    h8 bfr[13];
    {
        int n = nb + wn * 32 + l31;
        if (n >= NE_) n = NE_ - 1;          // clamp loads; stores masked below
        const float* ep = E + (size_t)n * DD_;
        #pragma unroll
        for (int ks = 0; ks < 13; ++ks) {
            const int k = ks * 16 + lh * 8;
            h8 v = {(_Float16)0, (_Float16)0, (_Float16)0, (_Float16)0,
                    (_Float16)0, (_Float16)0, (_Float16)0, (_Float16)0};
            if (k < DD_) {                  // ks==12,lh==1 (k=200) stays zero
                fx4 lo = *(const fx4*)(ep + k);
                fx4 hi = *(const fx4*)(ep + k + 4);
                v[0] = (_Float16)lo[0]; v[1] = (_Float16)lo[1];
                v[2] = (_Float16)lo[2]; v[3] = (_Float16)lo[3];
                v[4] = (_Float16)hi[0]; v[5] = (_Float16)hi[1];
                v[6] = (_Float16)hi[2]; v[7] = (_Float16)hi[3];
            }
            bfr[ks] = v;
        }
    }

    const int ncol = nb + wn * 32 + l31;
    const bool nok = (ncol < NE_);
    // staging assignment: 4 threads per row, 7 x 16B each
    const int srow = tid >> 2;              // 0..63
    const int scol = (tid & 3) * 8;         // element offset, +32 per j

    for (int c = 0; c < 16; ++c) {
        __syncthreads();                    // protect LDS from previous chunk
        const _Float16* gsrc = g16 + (size_t)(c * 64) * PP_;
        #pragma unroll
        for (int j = 0; j < 7; ++j)
            *(h8*)&Alds[srow * 232 + scol + j * 32] =
                *(const h8*)(gsrc + (size_t)srow * PP_ + scol + j * 32);
        __syncthreads();

        fx16 acc;
        #pragma unroll
        for (int i = 0; i < 16; ++i) acc[i] = 0.0f;

        #pragma unroll
        for (int ks = 0; ks < 13; ++ks) {
            // A[m=lane&31][k=ks*16 + lh*8 + j]
            h8 a = *(const h8*)&Alds[(wm * 32 + l31) * 232 + ks * 16 + lh * 8];
            acc = __builtin_amdgcn_mfma_f32_32x32x16_f16(a, bfr[ks], acc, 0, 0, 0);
        }

        // epilogue: sigmoid + store. row=(reg&3)+8*(reg>>2)+4*lh, col=lane&31
        if (nok) {
            const int mb = c * 64 + wm * 32 + lh * 4;
            #pragma unroll
            for (int r = 0; r < 16; ++r) {
                int m = mb + (r & 3) + 8 * (r >> 2);
                out[(size_t)m * NE_ + ncol] = fast_sigmoid(acc[r]);
            }
        }
    }
}

// ---------------------------------------------------------------------------
extern "C" void kernel_launch(void* const* d_in, const int* in_sizes, int n_in,
                              void* d_out, int out_size, void* d_ws, size_t ws_size,
                              hipStream_t stream)
{
    const int*   e1_idx = (const int*)  d_in[0];
    const int*   r_idx  = (const int*)  d_in[1];
    const int*   t_idx  = (const int*)  d_in[2];
    const float* E      = (const float*)d_in[3];
    const float* R      = (const float*)d_in[4];
    const float* T      = (const float*)d_in[5];
    const float* F0     = (const float*)d_in[6];
    const float* F1     = (const float*)d_in[7];
    const float* F2     = (const float*)d_in[8];
    const float* F3     = (const float*)d_in[9];
    float* out = (float*)d_out;

    // workspace layout (fp16): g (NB_ x PP_) only — FE is never materialized
    _Float16* g16 = (_Float16*)d_ws;

    prep_kernel<<<256, 256, 0, stream>>>(e1_idx, r_idx, t_idx, E, R, T,
                                         F0, F1, F2, F3, g16);

    const int nblocks = (NE_ + 63) / 64;   // 1563
    score_kernel<<<nblocks, 256, 0, stream>>>(g16, E, out);
}